// Round 10
// baseline (1449.755 us; speedup 1.0000x reference)
//
#include <hip/hip_runtime.h>
#include <hip/hip_bf16.h>

// Problem constants (B=4, V=4096, D=256, H=4, Dh=64, KNN=10, TOPK=4, HID=64)
#define VV 4096
#define DDIM 256
#define KNN_K 10
#define TK 4
#define G 8          // voxels per block

// fp32 helpers forbidding contraction (bit-faithful np mimicry — DO NOT CHANGE)
__device__ __forceinline__ float f_sq3(float x, float y, float z) {
    return __fadd_rn(__fadd_rn(__fmul_rn(x, x), __fmul_rn(y, y)), __fmul_rn(z, z));
}
__device__ __forceinline__ float f_dot3(float ax, float ay, float az,
                                        float bx, float by, float bz) {
    float d = __fmul_rn(ax, bx);
    d = __fmaf_rn(ay, by, d);
    d = __fmaf_rn(az, bz, d);
    return d;
}

// ---------------------------------------------------------------------------
// G=8 voxels per block (256 threads). Weights streamed once per block.
// Phase A: exact KNN per query (fp32-faithful d2, shuffle argmin, 1 barrier/iter)
// Phase B: score MLP (fp32-faithful FMA chains) + top-4 per query
// Phase C: joint 8-query Q/K/V k-loop, wave-butterfly QK, softmax, Wo epilogue
// ---------------------------------------------------------------------------
__global__ void __launch_bounds__(256) fused_voxel_attn_g8(
    const float* __restrict__ tok,
    const float* __restrict__ coords,
    const float* __restrict__ W1,
    const float* __restrict__ b1,
    const float* __restrict__ W2,
    const float* __restrict__ Wq, const float* __restrict__ bq,
    const float* __restrict__ Wk, const float* __restrict__ bk,
    const float* __restrict__ Wv, const float* __restrict__ bv,
    const float* __restrict__ Wo, const float* __restrict__ bo,
    float* __restrict__ out, int out_size)
{
    const int q0   = blockIdx.x * G;       // 2048 blocks; 8 consecutive voxels, same batch
    const int b    = q0 >> 12;
    const int base = q0 & ~4095;
    const int tid  = threadIdx.x;
    const int lane = tid & 63;
    const int wave = tid >> 6;
    const float* cb = coords + (size_t)b * VV * 3;

    __shared__ float sval2[2][4];
    __shared__ int   sidx2[2][4];
    __shared__ int   sKnn[G][KNN_K];
    __shared__ int   sSel[G][TK];
    __shared__ float sTokA[G][DDIM];        // 8 KB
    __shared__ float sAH[G][64];            // 2 KB
    __shared__ float sHid[KNN_K][64];       // 2.5 KB
    __shared__ float sSc[KNN_K];
    __shared__ float sPool[KNN_K * DDIM];   // 10 KB: phase-B neighbor tokens, later sO[G][256]
    __shared__ float sTokC[G][TK][DDIM];    // 32 KB: selected neighbor tokens

    // ================= Phase A: KNN per query =================
    for (int g = 0; g < G; g++) {
        const int v = (q0 + g) & 4095;
        const float qx = cb[v * 3 + 0];
        const float qy = cb[v * 3 + 1];
        const float qz = cb[v * 3 + 2];
        const float sqq = f_sq3(qx, qy, qz);

        float d2[16];
        #pragma unroll
        for (int i = 0; i < 16; i++) {
            int j = tid + i * 256;
            float xj = cb[j * 3 + 0], yj = cb[j * 3 + 1], zj = cb[j * 3 + 2];
            float sqj = f_sq3(xj, yj, zj);
            float dt  = f_dot3(qx, qy, qz, xj, yj, zj);
            d2[i] = __fsub_rn(__fadd_rn(sqq, sqj), __fmul_rn(2.0f, dt));
        }

        unsigned used = 0;
        for (int it = 0; it < 11; it++) {
            float best = 3.4e38f;
            int bi = 0x7fffffff;
            #pragma unroll
            for (int i = 0; i < 16; i++) {
                if (used & (1u << i)) continue;
                if (d2[i] < best) { best = d2[i]; bi = tid + i * 256; }  // strict <: lowest idx
            }
            // wave butterfly argmin (lexicographic (val, idx) — order-free)
            #pragma unroll
            for (int off = 1; off < 64; off <<= 1) {
                float v2 = __shfl_xor(best, off);
                int   i2 = __shfl_xor(bi,   off);
                if (v2 < best || (v2 == best && i2 < bi)) { best = v2; bi = i2; }
            }
            const int p = it & 1;
            if (lane == 0) { sval2[p][wave] = best; sidx2[p][wave] = bi; }
            __syncthreads();
            float fb = sval2[p][0]; int fi = sidx2[p][0];
            #pragma unroll
            for (int w2 = 1; w2 < 4; w2++) {
                float v2 = sval2[p][w2]; int i2 = sidx2[p][w2];
                if (v2 < fb || (v2 == fb && i2 < fi)) { fb = v2; fi = i2; }
            }
            int w = fi & 4095;    // clamp (defense only)
            if (it >= 1 && tid == 0) sKnn[g][it - 1] = w;
            if ((w & 255) == tid) used |= 1u << (w >> 8);
            // parity double-buffer: no second barrier needed
        }
        __syncthreads();   // publish sKnn[g]; also isolates d2/used between queries
    }

    // ================= Phase B: score MLP + top-4 =================
    #pragma unroll
    for (int g = 0; g < G; g++)
        sTokA[g][tid] = tok[(size_t)(q0 + g) * DDIM + tid];
    __syncthreads();

    // anchor prefix chains: 512 items (g,h); wave-uniform g, lane=h -> W1 coalesced
    for (int idx = tid; idx < G * 64; idx += 256) {
        int g = idx >> 6, h = idx & 63;
        float a = 0.0f;
        for (int k = 0; k < 256; k++)
            a = __fmaf_rn(sTokA[g][k], W1[k * 64 + h], a);
        sAH[g][h] = a;
    }
    __syncthreads();

    for (int g = 0; g < G; g++) {
        const int v = (q0 + g) & 4095;
        for (int nb = 0; nb < KNN_K; nb++)
            sPool[nb * DDIM + tid] = tok[(size_t)(base + sKnn[g][nb]) * DDIM + tid];
        __syncthreads();

        for (int idx = tid; idx < KNN_K * 64; idx += 256) {
            int nb = idx >> 6, h = idx & 63;
            float acc = sAH[g][h];
            const float* tn = &sPool[nb * DDIM];
            for (int k = 0; k < 256; k++)
                acc = __fmaf_rn(tn[k], W1[(256 + k) * 64 + h], acc);
            #pragma unroll
            for (int c = 0; c < 3; c++) {
                float rel = __fsub_rn(cb[sKnn[g][nb] * 3 + c], cb[v * 3 + c]);
                acc = __fmaf_rn(rel, W1[(512 + c) * 64 + h], acc);
            }
            float hid = __fadd_rn(acc, b1[h]);
            sHid[nb][h] = hid > 0.0f ? hid : 0.0f;
        }
        __syncthreads();

        if (tid < KNN_K) {
            float s = 0.0f;
            for (int h = 0; h < 64; h++)
                s = __fmaf_rn(sHid[tid][h], W2[h], s);
            sSc[tid] = s;
        }
        __syncthreads();

        if (tid == 0) {
            unsigned um = 0;
            #pragma unroll
            for (int s = 0; s < TK; s++) {
                float best = -3.4e38f; int bj = 0;
                for (int jj = 0; jj < KNN_K; jj++) {
                    if (um & (1u << jj)) continue;
                    if (sSc[jj] > best) { best = sSc[jj]; bj = jj; }
                }
                um |= 1u << bj;
                sSel[g][s] = bj;
            }
        }
        __syncthreads();

        #pragma unroll
        for (int s = 0; s < TK; s++)
            sTokC[g][s][tid] = sPool[sSel[g][s] * DDIM + tid];
        __syncthreads();   // before next g overwrites sPool
    }

    // ================= Phase C: joint QKV + attention + Wo =================
    float q_acc[G], k_acc[G][TK], v_acc[G][TK];
    #pragma unroll
    for (int g = 0; g < G; g++) {
        q_acc[g] = bq[tid];
        #pragma unroll
        for (int s = 0; s < TK; s++) { k_acc[g][s] = bk[tid]; v_acc[g][s] = bv[tid]; }
    }

    for (int k4 = 0; k4 < 64; k4++) {
        const int k = k4 * 4;
        float wq0 = Wq[(k + 0) * 256 + tid], wq1 = Wq[(k + 1) * 256 + tid],
              wq2 = Wq[(k + 2) * 256 + tid], wq3 = Wq[(k + 3) * 256 + tid];
        float wk0 = Wk[(k + 0) * 256 + tid], wk1 = Wk[(k + 1) * 256 + tid],
              wk2 = Wk[(k + 2) * 256 + tid], wk3 = Wk[(k + 3) * 256 + tid];
        float wv0 = Wv[(k + 0) * 256 + tid], wv1 = Wv[(k + 1) * 256 + tid],
              wv2 = Wv[(k + 2) * 256 + tid], wv3 = Wv[(k + 3) * 256 + tid];
        #pragma unroll
        for (int g = 0; g < G; g++) {
            float4 xa = ((const float4*)sTokA[g])[k4];
            q_acc[g] = fmaf(xa.x, wq0, q_acc[g]);
            q_acc[g] = fmaf(xa.y, wq1, q_acc[g]);
            q_acc[g] = fmaf(xa.z, wq2, q_acc[g]);
            q_acc[g] = fmaf(xa.w, wq3, q_acc[g]);
            #pragma unroll
            for (int s = 0; s < TK; s++) {
                float4 xn = ((const float4*)sTokC[g][s])[k4];
                k_acc[g][s] = fmaf(xn.x, wk0, k_acc[g][s]);
                k_acc[g][s] = fmaf(xn.y, wk1, k_acc[g][s]);
                k_acc[g][s] = fmaf(xn.z, wk2, k_acc[g][s]);
                k_acc[g][s] = fmaf(xn.w, wk3, k_acc[g][s]);
                v_acc[g][s] = fmaf(xn.x, wv0, v_acc[g][s]);
                v_acc[g][s] = fmaf(xn.y, wv1, v_acc[g][s]);
                v_acc[g][s] = fmaf(xn.z, wv2, v_acc[g][s]);
                v_acc[g][s] = fmaf(xn.w, wv3, v_acc[g][s]);
            }
        }
    }

    // QK dots (wave = head), softmax, weighted V; sO into sPool region
    #pragma unroll
    for (int g = 0; g < G; g++) {
        float att[TK];
        #pragma unroll
        for (int s = 0; s < TK; s++) {
            float p = q_acc[g] * k_acc[g][s];
            #pragma unroll
            for (int m = 1; m < 64; m <<= 1) p += __shfl_xor(p, m);
            att[s] = p * 0.125f;   // 1/sqrt(64)
        }
        float mx  = fmaxf(fmaxf(att[0], att[1]), fmaxf(att[2], att[3]));
        float e0 = expf(att[0] - mx), e1 = expf(att[1] - mx),
              e2 = expf(att[2] - mx), e3 = expf(att[3] - mx);
        float inv = 1.0f / (e0 + e1 + e2 + e3);
        sPool[g * DDIM + tid] = (e0 * v_acc[g][0] + e1 * v_acc[g][1] +
                                 e2 * v_acc[g][2] + e3 * v_acc[g][3]) * inv;
    }
    __syncthreads();

    float a[G];
    #pragma unroll
    for (int g = 0; g < G; g++) a[g] = bo[tid];
    for (int e4 = 0; e4 < 64; e4++) {
        const int e = e4 * 4;
        float wo0 = Wo[(e + 0) * 256 + tid], wo1 = Wo[(e + 1) * 256 + tid],
              wo2 = Wo[(e + 2) * 256 + tid], wo3 = Wo[(e + 3) * 256 + tid];
        #pragma unroll
        for (int g = 0; g < G; g++) {
            float4 so = ((const float4*)&sPool[g * DDIM])[e4];
            a[g] = fmaf(so.x, wo0, a[g]);
            a[g] = fmaf(so.y, wo1, a[g]);
            a[g] = fmaf(so.z, wo2, a[g]);
            a[g] = fmaf(so.w, wo3, a[g]);
        }
    }
    #pragma unroll
    for (int g = 0; g < G; g++) {
        int oidx = (q0 + g) * DDIM + tid;
        if (oidx < out_size) out[oidx] = a[g];
    }
}

// ---------------------------------------------------------------------------
// Launcher: ABI-bilingual ordered size-walk (validated in rounds 8-9).
// ---------------------------------------------------------------------------
extern "C" void kernel_launch(void* const* d_in, const int* in_sizes, int n_in,
                              void* d_out, int out_size, void* d_ws, size_t ws_size,
                              hipStream_t stream)
{
    (void)d_ws; (void)ws_size;

    const long long want[13] = {4194304LL, 49152LL, 32960LL, 64LL, 64LL,
                                65536LL, 256LL, 65536LL, 256LL,
                                65536LL, 256LL, 65536LL, 256LL};
    int idx[13];
    const int n = n_in;

    const long long* s64 = (const long long*)(const void*)in_sizes;
    const int*       s32 = in_sizes;

    bool ok = false;

    if (n >= 13 && s64[0] == want[0]) {   // int64 interpretation (gated)
        ok = true;
        int walk = 0;
        for (int t = 0; t < 13; t++) {
            int f = -1;
            for (int i = walk; i < n; i++) {
                if (s64[i] == want[t]) { f = i; break; }
            }
            if (f < 0) { ok = false; break; }
            idx[t] = f; walk = f + 1;
        }
    }

    if (!ok) {                            // int32 interpretation
        ok = true;
        int walk = 0;
        for (int t = 0; t < 13; t++) {
            int f = -1;
            for (int i = walk; i < n; i++) {
                if ((long long)s32[i] == want[t]) { f = i; break; }
            }
            if (f < 0) { ok = false; break; }
            idx[t] = f; walk = f + 1;
        }
    }

    if (!ok) return;   // unexpected layout: clean failure, no crash

    fused_voxel_attn_g8<<<dim3(16384 / G), dim3(256), 0, stream>>>(
        (const float*)d_in[idx[0]],                           // tok
        (const float*)d_in[idx[1]],                           // coords
        (const float*)d_in[idx[2]],                           // W1
        (const float*)d_in[idx[3]],                           // b1
        (const float*)d_in[idx[4]],                           // W2
        (const float*)d_in[idx[5]],  (const float*)d_in[idx[6]],   // Wq, bq
        (const float*)d_in[idx[7]],  (const float*)d_in[idx[8]],   // Wk, bk
        (const float*)d_in[idx[9]],  (const float*)d_in[idx[10]],  // Wv, bv
        (const float*)d_in[idx[11]], (const float*)d_in[idx[12]],  // Wo, bo
        (float*)d_out, out_size);
}

// Round 11
// 666.783 us; speedup vs baseline: 2.1743x; 2.1743x over previous
//
#include <hip/hip_runtime.h>
#include <hip/hip_bf16.h>

// Problem constants (B=4, V=4096, D=256, H=4, Dh=64, KNN=10, TOPK=4, HID=64)
#define VV 4096
#define DDIM 256
#define KNN_K 10
#define TK 4

// fp32 helpers forbidding contraction (bit-faithful np mimicry — DO NOT CHANGE)
__device__ __forceinline__ float f_sq3(float x, float y, float z) {
    return __fadd_rn(__fadd_rn(__fmul_rn(x, x), __fmul_rn(y, y)), __fmul_rn(z, z));
}
__device__ __forceinline__ float f_dot3(float ax, float ay, float az,
                                        float bx, float by, float bz) {
    float d = __fmul_rn(ax, bx);
    d = __fmaf_rn(ay, by, d);
    d = __fmaf_rn(az, bz, d);
    return d;
}

// ===========================================================================
// K1: KNN + score-MLP + top-4 selection (bit-faithful fp32, validated r9/r10).
// One block (256 threads) per voxel; ~15 KB LDS -> high occupancy.
// Writes sel[q][s] = GLOBAL token row of the s-th selected neighbor.
// ===========================================================================
__global__ void __launch_bounds__(256) knn_score_kernel(
    const float* __restrict__ tok,
    const float* __restrict__ coords,
    const float* __restrict__ W1,
    const float* __restrict__ b1,
    const float* __restrict__ W2,
    int* __restrict__ sel)
{
    const int q    = blockIdx.x;       // 0..16383
    const int b    = q >> 12;
    const int v    = q & 4095;
    const int base = q & ~4095;
    const int tid  = threadIdx.x;
    const int lane = tid & 63;
    const int wave = tid >> 6;
    const float* cb = coords + (size_t)b * VV * 3;

    __shared__ float sval2[2][4];
    __shared__ int   sidx2[2][4];
    __shared__ int   sKnn[KNN_K];
    __shared__ float sTokA[DDIM];
    __shared__ float sTokN[KNN_K][DDIM];
    __shared__ float sAH[64];
    __shared__ float sHid[KNN_K][64];
    __shared__ float sSc[KNN_K];

    // ---------------- Phase A: KNN, faithful fp32 d2 ----------------
    const float qx = cb[v * 3 + 0];
    const float qy = cb[v * 3 + 1];
    const float qz = cb[v * 3 + 2];
    const float sqq = f_sq3(qx, qy, qz);

    float d2[16];
    #pragma unroll
    for (int i = 0; i < 16; i++) {
        int j = tid + i * 256;
        float xj = cb[j * 3 + 0], yj = cb[j * 3 + 1], zj = cb[j * 3 + 2];
        float sqj = f_sq3(xj, yj, zj);
        float dt  = f_dot3(qx, qy, qz, xj, yj, zj);
        d2[i] = __fsub_rn(__fadd_rn(sqq, sqj), __fmul_rn(2.0f, dt));
    }

    unsigned used = 0;
    for (int it = 0; it < 11; it++) {
        float best = 3.4e38f;
        int bi = 0x7fffffff;
        #pragma unroll
        for (int i = 0; i < 16; i++) {
            if (used & (1u << i)) continue;
            if (d2[i] < best) { best = d2[i]; bi = tid + i * 256; }  // strict <: lowest idx
        }
        #pragma unroll
        for (int off = 1; off < 64; off <<= 1) {      // wave butterfly argmin (order-free)
            float v2 = __shfl_xor(best, off);
            int   i2 = __shfl_xor(bi,   off);
            if (v2 < best || (v2 == best && i2 < bi)) { best = v2; bi = i2; }
        }
        const int p = it & 1;
        if (lane == 0) { sval2[p][wave] = best; sidx2[p][wave] = bi; }
        __syncthreads();
        float fb = sval2[p][0]; int fi = sidx2[p][0];
        #pragma unroll
        for (int w2 = 1; w2 < 4; w2++) {
            float v2 = sval2[p][w2]; int i2 = sidx2[p][w2];
            if (v2 < fb || (v2 == fb && i2 < fi)) { fb = v2; fi = i2; }
        }
        int w = fi & 4095;    // defense clamp
        if (it >= 1 && tid == 0) sKnn[it - 1] = w;
        if ((w & 255) == tid) used |= 1u << (w >> 8);
        // parity double-buffer: next iter writes the other slot, 1 barrier/iter
    }
    __syncthreads();          // publish sKnn

    // ---------------- Phase B: score MLP, faithful fp32 ----------------
    sTokA[tid] = tok[(size_t)q * DDIM + tid];
    for (int nb = 0; nb < KNN_K; nb++)
        sTokN[nb][tid] = tok[(size_t)(base + sKnn[nb]) * DDIM + tid];
    __syncthreads();

    if (tid < 64) {           // anchor-prefix chain (identical rounding for all nb)
        float a = 0.0f;
        for (int k = 0; k < 256; k++)
            a = __fmaf_rn(sTokA[k], W1[k * 64 + tid], a);
        sAH[tid] = a;
    }
    __syncthreads();

    for (int idx = tid; idx < KNN_K * 64; idx += 256) {
        int nb = idx >> 6, h = idx & 63;
        float acc = sAH[h];
        const float* tn = sTokN[nb];
        for (int k = 0; k < 256; k++)
            acc = __fmaf_rn(tn[k], W1[(256 + k) * 64 + h], acc);
        #pragma unroll
        for (int c = 0; c < 3; c++) {
            float rel = __fsub_rn(cb[sKnn[nb] * 3 + c], cb[v * 3 + c]);
            acc = __fmaf_rn(rel, W1[(512 + c) * 64 + h], acc);
        }
        float hid = __fadd_rn(acc, b1[h]);
        sHid[nb][h] = hid > 0.0f ? hid : 0.0f;
    }
    __syncthreads();

    if (tid < KNN_K) {
        float s = 0.0f;
        for (int h = 0; h < 64; h++)
            s = __fmaf_rn(sHid[tid][h], W2[h], s);
        sSc[tid] = s;
    }
    __syncthreads();

    if (tid == 0) {           // stable top-4 -> global rows
        unsigned um = 0;
        #pragma unroll
        for (int s = 0; s < TK; s++) {
            float best = -3.4e38f; int bj = 0;
            for (int jj = 0; jj < KNN_K; jj++) {
                if (um & (1u << jj)) continue;
                if (sSc[jj] > best) { best = sSc[jj]; bj = jj; }
            }
            um |= 1u << bj;
            sel[(size_t)q * TK + s] = base + sKnn[bj];
        }
    }
}

// ===========================================================================
// K2: dense QKV projection GEMM. qkv[m][g*256+n] = tok[m,:] @ Wg[:,n] + bg[n]
// M=16384, N=768 (Q|K|V), K=256. grid(256,12), block 256, 64x64/BK16/4x4.
// Magnitude path: accumulation order free.
// ===========================================================================
__global__ void __launch_bounds__(256) qkv_gemm_kernel(
    const float* __restrict__ tok,
    const float* __restrict__ Wq, const float* __restrict__ bq,
    const float* __restrict__ Wk, const float* __restrict__ bk,
    const float* __restrict__ Wv, const float* __restrict__ bv,
    float* __restrict__ qkv)
{
    __shared__ float As[16][68];   // [k][m]
    __shared__ float Bs[16][68];   // [k][n]

    const int mBlock = blockIdx.x * 64;
    const int nBlock = blockIdx.y * 64;      // 0..704
    const int grp = nBlock >> 8;             // 0=Q,1=K,2=V
    const int nIn = nBlock & 255;
    const float* W    = (grp == 0) ? Wq : (grp == 1) ? Wk : Wv;
    const float* bias = (grp == 0) ? bq : (grp == 1) ? bk : bv;

    const int tid = threadIdx.x;
    const int tx = tid & 15;     // n-dir
    const int ty = tid >> 4;     // m-dir

    const int ar  = tid >> 2;          // 0..63 (m row)
    const int ac4 = tid & 3;           // 0..3  (k float4)
    const int br  = tid >> 4;          // 0..15 (k row)
    const int bc4 = tid & 15;          // 0..15 (n float4)

    float acc[4][4] = {};

    for (int k0 = 0; k0 < 256; k0 += 16) {
        float4 a4 = *(const float4*)&tok[(size_t)(mBlock + ar) * 256 + k0 + ac4 * 4];
        As[ac4 * 4 + 0][ar] = a4.x;
        As[ac4 * 4 + 1][ar] = a4.y;
        As[ac4 * 4 + 2][ar] = a4.z;
        As[ac4 * 4 + 3][ar] = a4.w;
        float4 b4 = *(const float4*)&W[(size_t)(k0 + br) * 256 + nIn + bc4 * 4];
        *(float4*)&Bs[br][bc4 * 4] = b4;
        __syncthreads();
        #pragma unroll
        for (int kk = 0; kk < 16; kk++) {
            float4 av = *(const float4*)&As[kk][ty * 4];
            float4 bv4 = *(const float4*)&Bs[kk][tx * 4];
            acc[0][0] = fmaf(av.x, bv4.x, acc[0][0]); acc[0][1] = fmaf(av.x, bv4.y, acc[0][1]);
            acc[0][2] = fmaf(av.x, bv4.z, acc[0][2]); acc[0][3] = fmaf(av.x, bv4.w, acc[0][3]);
            acc[1][0] = fmaf(av.y, bv4.x, acc[1][0]); acc[1][1] = fmaf(av.y, bv4.y, acc[1][1]);
            acc[1][2] = fmaf(av.y, bv4.z, acc[1][2]); acc[1][3] = fmaf(av.y, bv4.w, acc[1][3]);
            acc[2][0] = fmaf(av.z, bv4.x, acc[2][0]); acc[2][1] = fmaf(av.z, bv4.y, acc[2][1]);
            acc[2][2] = fmaf(av.z, bv4.z, acc[2][2]); acc[2][3] = fmaf(av.z, bv4.w, acc[2][3]);
            acc[3][0] = fmaf(av.w, bv4.x, acc[3][0]); acc[3][1] = fmaf(av.w, bv4.y, acc[3][1]);
            acc[3][2] = fmaf(av.w, bv4.z, acc[3][2]); acc[3][3] = fmaf(av.w, bv4.w, acc[3][3]);
        }
        __syncthreads();
    }

    #pragma unroll
    for (int i = 0; i < 4; i++) {
        int m = mBlock + ty * 4 + i;
        float4 o;
        o.x = acc[i][0] + bias[nIn + tx * 4 + 0];
        o.y = acc[i][1] + bias[nIn + tx * 4 + 1];
        o.z = acc[i][2] + bias[nIn + tx * 4 + 2];
        o.w = acc[i][3] + bias[nIn + tx * 4 + 3];
        *(float4*)&qkv[(size_t)m * 768 + nBlock + tx * 4] = o;
    }
}

// ===========================================================================
// K3: gather 4 selected K/V rows, 4-head attention -> attnout[q][256].
// Block 256 = 4 waves (= heads). Magnitude path (butterfly order free).
// ===========================================================================
__global__ void __launch_bounds__(256) attn_gather_kernel(
    const float* __restrict__ qkv, const int* __restrict__ sel,
    float* __restrict__ attnout)
{
    const int q = blockIdx.x;
    const int tid = threadIdx.x;  // = h*64 + dh

    const float qv = qkv[(size_t)q * 768 + tid];

    int rows[TK];
    #pragma unroll
    for (int s = 0; s < TK; s++) rows[s] = sel[(size_t)q * TK + s];

    float att[TK];
    #pragma unroll
    for (int s = 0; s < TK; s++) {
        float p = qv * qkv[(size_t)rows[s] * 768 + 256 + tid];
        #pragma unroll
        for (int m = 1; m < 64; m <<= 1) p += __shfl_xor(p, m);
        att[s] = p * 0.125f;   // 1/sqrt(64)
    }

    float mx  = fmaxf(fmaxf(att[0], att[1]), fmaxf(att[2], att[3]));
    float e0 = expf(att[0] - mx), e1 = expf(att[1] - mx),
          e2 = expf(att[2] - mx), e3 = expf(att[3] - mx);
    float inv = 1.0f / (e0 + e1 + e2 + e3);

    float o = (e0 * qkv[(size_t)rows[0] * 768 + 512 + tid] +
               e1 * qkv[(size_t)rows[1] * 768 + 512 + tid] +
               e2 * qkv[(size_t)rows[2] * 768 + 512 + tid] +
               e3 * qkv[(size_t)rows[3] * 768 + 512 + tid]) * inv;

    attnout[(size_t)q * 256 + tid] = o;
}

// ===========================================================================
// K4: output projection GEMM. out = attnout @ Wo + bo. M=16384,N=256,K=256.
// grid(256,4), same tile structure as K2.
// ===========================================================================
__global__ void __launch_bounds__(256) wo_gemm_kernel(
    const float* __restrict__ A,
    const float* __restrict__ Wo, const float* __restrict__ bo,
    float* __restrict__ out)
{
    __shared__ float As[16][68];
    __shared__ float Bs[16][68];

    const int mBlock = blockIdx.x * 64;
    const int nBlock = blockIdx.y * 64;      // 0..192

    const int tid = threadIdx.x;
    const int tx = tid & 15;
    const int ty = tid >> 4;

    const int ar  = tid >> 2;
    const int ac4 = tid & 3;
    const int br  = tid >> 4;
    const int bc4 = tid & 15;

    float acc[4][4] = {};

    for (int k0 = 0; k0 < 256; k0 += 16) {
        float4 a4 = *(const float4*)&A[(size_t)(mBlock + ar) * 256 + k0 + ac4 * 4];
        As[ac4 * 4 + 0][ar] = a4.x;
        As[ac4 * 4 + 1][ar] = a4.y;
        As[ac4 * 4 + 2][ar] = a4.z;
        As[ac4 * 4 + 3][ar] = a4.w;
        float4 b4 = *(const float4*)&Wo[(size_t)(k0 + br) * 256 + nBlock + bc4 * 4];
        *(float4*)&Bs[br][bc4 * 4] = b4;
        __syncthreads();
        #pragma unroll
        for (int kk = 0; kk < 16; kk++) {
            float4 av = *(const float4*)&As[kk][ty * 4];
            float4 bv4 = *(const float4*)&Bs[kk][tx * 4];
            acc[0][0] = fmaf(av.x, bv4.x, acc[0][0]); acc[0][1] = fmaf(av.x, bv4.y, acc[0][1]);
            acc[0][2] = fmaf(av.x, bv4.z, acc[0][2]); acc[0][3] = fmaf(av.x, bv4.w, acc[0][3]);
            acc[1][0] = fmaf(av.y, bv4.x, acc[1][0]); acc[1][1] = fmaf(av.y, bv4.y, acc[1][1]);
            acc[1][2] = fmaf(av.y, bv4.z, acc[1][2]); acc[1][3] = fmaf(av.y, bv4.w, acc[1][3]);
            acc[2][0] = fmaf(av.z, bv4.x, acc[2][0]); acc[2][1] = fmaf(av.z, bv4.y, acc[2][1]);
            acc[2][2] = fmaf(av.z, bv4.z, acc[2][2]); acc[2][3] = fmaf(av.z, bv4.w, acc[2][3]);
            acc[3][0] = fmaf(av.w, bv4.x, acc[3][0]); acc[3][1] = fmaf(av.w, bv4.y, acc[3][1]);
            acc[3][2] = fmaf(av.w, bv4.z, acc[3][2]); acc[3][3] = fmaf(av.w, bv4.w, acc[3][3]);
        }
        __syncthreads();
    }

    #pragma unroll
    for (int i = 0; i < 4; i++) {
        int m = mBlock + ty * 4 + i;
        float4 o;
        o.x = acc[i][0] + bo[nBlock + tx * 4 + 0];
        o.y = acc[i][1] + bo[nBlock + tx * 4 + 1];
        o.z = acc[i][2] + bo[nBlock + tx * 4 + 2];
        o.w = acc[i][3] + bo[nBlock + tx * 4 + 3];
        *(float4*)&out[(size_t)m * 256 + nBlock + tx * 4] = o;
    }
}

// ===========================================================================
// Fallback: round-9 fully fused kernel (PASSED @1050us), used if ws too small.
// ===========================================================================
__global__ void __launch_bounds__(256) fused_voxel_attn(
    const float* __restrict__ tok,
    const float* __restrict__ coords,
    const float* __restrict__ W1,
    const float* __restrict__ b1,
    const float* __restrict__ W2,
    const float* __restrict__ Wq, const float* __restrict__ bq,
    const float* __restrict__ Wk, const float* __restrict__ bk,
    const float* __restrict__ Wv, const float* __restrict__ bv,
    const float* __restrict__ Wo, const float* __restrict__ bo,
    float* __restrict__ out, int out_size)
{
    const int q    = blockIdx.x;
    const int b    = q >> 12;
    const int v    = q & 4095;
    const int base = q & ~4095;
    const int tid  = threadIdx.x;
    const float* cb = coords + (size_t)b * VV * 3;

    __shared__ float  sval[256];
    __shared__ int    sidx[256];
    __shared__ int    sKnn[KNN_K];
    __shared__ int    sSel[TK];
    __shared__ float  sTokA[DDIM];
    __shared__ float  sTokN[KNN_K][DDIM];
    __shared__ float  sAH[64];
    __shared__ float  sHid[KNN_K][64];
    __shared__ float  sSc[KNN_K];
    __shared__ float  sP[TK][256];
    __shared__ float  sAtt[4][TK];
    __shared__ float  sO[DDIM];

    const float qx = cb[v * 3 + 0];
    const float qy = cb[v * 3 + 1];
    const float qz = cb[v * 3 + 2];
    const float sqq = f_sq3(qx, qy, qz);

    float d2[16];
    #pragma unroll
    for (int i = 0; i < 16; i++) {
        int j = tid + i * 256;
        float xj = cb[j * 3 + 0], yj = cb[j * 3 + 1], zj = cb[j * 3 + 2];
        float sqj = f_sq3(xj, yj, zj);
        float dt  = f_dot3(qx, qy, qz, xj, yj, zj);
        d2[i] = __fsub_rn(__fadd_rn(sqq, sqj), __fmul_rn(2.0f, dt));
    }

    unsigned used = 0;
    for (int it = 0; it < 11; it++) {
        float best = 3.4e38f;
        int bi = 0x7fffffff;
        #pragma unroll
        for (int i = 0; i < 16; i++) {
            if (used & (1u << i)) continue;
            if (d2[i] < best) { best = d2[i]; bi = tid + i * 256; }
        }
        sval[tid] = best;
        sidx[tid] = bi;
        __syncthreads();
        for (int s = 128; s > 0; s >>= 1) {
            if (tid < s) {
                float v2 = sval[tid + s];
                int   i2 = sidx[tid + s];
                if (v2 < sval[tid] || (v2 == sval[tid] && i2 < sidx[tid])) {
                    sval[tid] = v2; sidx[tid] = i2;
                }
            }
            __syncthreads();
        }
        int w = sidx[0] & 4095;
        __syncthreads();
        if (it >= 1 && tid == 0) sKnn[it - 1] = w;
        if ((w & 255) == tid) used |= 1u << (w >> 8);
    }
    __syncthreads();

    sTokA[tid] = tok[(size_t)q * DDIM + tid];
    for (int nb = 0; nb < KNN_K; nb++)
        sTokN[nb][tid] = tok[(size_t)(base + sKnn[nb]) * DDIM + tid];
    __syncthreads();

    if (tid < 64) {
        float a = 0.0f;
        for (int k = 0; k < 256; k++)
            a = __fmaf_rn(sTokA[k], W1[k * 64 + tid], a);
        sAH[tid] = a;
    }
    __syncthreads();

    for (int idx = tid; idx < KNN_K * 64; idx += 256) {
        int nb = idx >> 6;
        int h  = idx & 63;
        float acc = sAH[h];
        const float* tn = sTokN[nb];
        for (int k = 0; k < 256; k++)
            acc = __fmaf_rn(tn[k], W1[(256 + k) * 64 + h], acc);
        #pragma unroll
        for (int c = 0; c < 3; c++) {
            float rel = __fsub_rn(cb[sKnn[nb] * 3 + c], cb[v * 3 + c]);
            acc = __fmaf_rn(rel, W1[(512 + c) * 64 + h], acc);
        }
        float hid = __fadd_rn(acc, b1[h]);
        sHid[nb][h] = hid > 0.0f ? hid : 0.0f;
    }
    __syncthreads();

    if (tid < KNN_K) {
        float s = 0.0f;
        for (int h = 0; h < 64; h++)
            s = __fmaf_rn(sHid[tid][h], W2[h], s);
        sSc[tid] = s;
    }
    __syncthreads();

    if (tid == 0) {
        unsigned um = 0;
        #pragma unroll
        for (int s = 0; s < TK; s++) {
            float best = -3.4e38f; int bj = 0;
            for (int jj = 0; jj < KNN_K; jj++) {
                if (um & (1u << jj)) continue;
                if (sSc[jj] > best) { best = sSc[jj]; bj = jj; }
            }
            um |= 1u << bj;
            sSel[s] = bj;
        }
    }
    __syncthreads();

    int ss[TK];
    float k_acc[TK], v_acc[TK];
    #pragma unroll
    for (int s = 0; s < TK; s++) {
        ss[s] = sSel[s];
        k_acc[s] = bk[tid];
        v_acc[s] = bv[tid];
    }
    float q_acc = bq[tid];

    for (int k = 0; k < 256; k++) {
        float wq = Wq[k * 256 + tid];
        float wk = Wk[k * 256 + tid];
        float wv = Wv[k * 256 + tid];
        q_acc += sTokA[k] * wq;
        #pragma unroll
        for (int s = 0; s < TK; s++) {
            float x = sTokN[ss[s]][k];
            k_acc[s] += x * wk;
            v_acc[s] += x * wv;
        }
    }

    #pragma unroll
    for (int s = 0; s < TK; s++) sP[s][tid] = q_acc * k_acc[s];
    __syncthreads();

    if (tid < 16) {
        int h = tid >> 2, s = tid & 3;
        float p = 0.0f;
        for (int d = 0; d < 64; d++) p += sP[s][h * 64 + d];
        sAtt[h][s] = p * 0.125f;
    }
    __syncthreads();

    const int hh = tid >> 6;
    float a0 = sAtt[hh][0], a1 = sAtt[hh][1], a2 = sAtt[hh][2], a3 = sAtt[hh][3];
    float mx  = fmaxf(fmaxf(a0, a1), fmaxf(a2, a3));
    float e0 = expf(a0 - mx), e1 = expf(a1 - mx), e2 = expf(a2 - mx), e3 = expf(a3 - mx);
    float inv = 1.0f / (e0 + e1 + e2 + e3);
    float o = (e0 * v_acc[0] + e1 * v_acc[1] + e2 * v_acc[2] + e3 * v_acc[3]) * inv;

    sO[tid] = o;
    __syncthreads();

    float a = bo[tid];
    for (int e = 0; e < 256; e++) a += sO[e] * Wo[e * 256 + tid];
    int oidx = q * DDIM + tid;
    if (oidx < out_size)
        out[oidx] = a;
}

// ---------------------------------------------------------------------------
// Launcher. ABI-bilingual size-walk (validated r8-r10). ws layout:
//   sel     @ 0        : 16384*4*4   =   262,144
//   qkv     @ 4 MiB    : 16384*768*4 = 50,331,648  (ends 54,525,952)
//   attnout @ 56 MiB   : 16384*256*4 = 16,777,216  (ends 75,497,472)
// If ws_size < 75,497,472 -> fallback to the fused r9 kernel (constant branch).
// ---------------------------------------------------------------------------
extern "C" void kernel_launch(void* const* d_in, const int* in_sizes, int n_in,
                              void* d_out, int out_size, void* d_ws, size_t ws_size,
                              hipStream_t stream)
{
    const long long want[13] = {4194304LL, 49152LL, 32960LL, 64LL, 64LL,
                                65536LL, 256LL, 65536LL, 256LL,
                                65536LL, 256LL, 65536LL, 256LL};
    int idx[13];
    const int n = n_in;

    const long long* s64 = (const long long*)(const void*)in_sizes;
    const int*       s32 = in_sizes;

    bool ok = false;

    if (n >= 13 && s64[0] == want[0]) {   // int64 interpretation (gated)
        ok = true;
        int walk = 0;
        for (int t = 0; t < 13; t++) {
            int f = -1;
            for (int i = walk; i < n; i++) {
                if (s64[i] == want[t]) { f = i; break; }
            }
            if (f < 0) { ok = false; break; }
            idx[t] = f; walk = f + 1;
        }
    }

    if (!ok) {                            // int32 interpretation
        ok = true;
        int walk = 0;
        for (int t = 0; t < 13; t++) {
            int f = -1;
            for (int i = walk; i < n; i++) {
                if ((long long)s32[i] == want[t]) { f = i; break; }
            }
            if (f < 0) { ok = false; break; }
            idx[t] = f; walk = f + 1;
        }
    }

    if (!ok) return;   // unexpected layout: clean failure, no crash

    const float* tok    = (const float*)d_in[idx[0]];
    const float* coords = (const float*)d_in[idx[1]];
    const float* W1     = (const float*)d_in[idx[2]];
    const float* b1     = (const float*)d_in[idx[3]];
    const float* W2     = (const float*)d_in[idx[4]];
    const float* Wq     = (const float*)d_in[idx[5]];
    const float* bq     = (const float*)d_in[idx[6]];
    const float* Wk     = (const float*)d_in[idx[7]];
    const float* bk     = (const float*)d_in[idx[8]];
    const float* Wv     = (const float*)d_in[idx[9]];
    const float* bv     = (const float*)d_in[idx[10]];
    const float* Wo     = (const float*)d_in[idx[11]];
    const float* bo     = (const float*)d_in[idx[12]];
    float* out = (float*)d_out;

    const size_t NEED = 75497472;   // attnout end
    if (ws_size >= NEED) {
        char* ws = (char*)d_ws;
        int*   sel     = (int*)  (ws + 0);
        float* qkv     = (float*)(ws + 4194304);
        float* attnout = (float*)(ws + 58720256);

        knn_score_kernel<<<dim3(16384), dim3(256), 0, stream>>>(tok, coords, W1, b1, W2, sel);
        qkv_gemm_kernel<<<dim3(256, 12), dim3(256), 0, stream>>>(tok, Wq, bq, Wk, bk, Wv, bv, qkv);
        attn_gather_kernel<<<dim3(16384), dim3(256), 0, stream>>>(qkv, sel, attnout);
        wo_gemm_kernel<<<dim3(256, 4), dim3(256), 0, stream>>>(attnout, Wo, bo, out);
    } else {
        fused_voxel_attn<<<dim3(16384), dim3(256), 0, stream>>>(
            tok, coords, W1, b1, W2, Wq, bq, Wk, bk, Wv, bv, Wo, bo, out, out_size);
    }
}

// Round 12
// 622.456 us; speedup vs baseline: 2.3291x; 1.0712x over previous
//
#include <hip/hip_runtime.h>
#include <hip/hip_bf16.h>

// Problem constants (B=4, V=4096, D=256, H=4, Dh=64, KNN=10, TOPK=4, HID=64)
#define VV 4096
#define DDIM 256
#define KNN_K 10
#define TK 4

// fp32 helpers forbidding contraction (bit-faithful np mimicry — DO NOT CHANGE)
__device__ __forceinline__ float f_sq3(float x, float y, float z) {
    return __fadd_rn(__fadd_rn(__fmul_rn(x, x), __fmul_rn(y, y)), __fmul_rn(z, z));
}
__device__ __forceinline__ float f_dot3(float ax, float ay, float az,
                                        float bx, float by, float bz) {
    float d = __fmul_rn(ax, bx);
    d = __fmaf_rn(ay, by, d);
    d = __fmaf_rn(az, bz, d);
    return d;
}

// ===========================================================================
// K1: KNN + score-MLP + top-4 selection (bit-faithful fp32).
// r12: cached-best argmin (only winner rescans) + unrolled pointer-walk
// FMA chains. Selection results bit-identical to r9-r11.
// ===========================================================================
__global__ void __launch_bounds__(256) knn_score_kernel(
    const float* __restrict__ tok,
    const float* __restrict__ coords,
    const float* __restrict__ W1,
    const float* __restrict__ b1,
    const float* __restrict__ W2,
    int* __restrict__ sel)
{
    const int q    = blockIdx.x;       // 0..16383
    const int b    = q >> 12;
    const int v    = q & 4095;
    const int base = q & ~4095;
    const int tid  = threadIdx.x;
    const int lane = tid & 63;
    const int wave = tid >> 6;
    const float* cb = coords + (size_t)b * VV * 3;

    __shared__ float sval2[2][4];
    __shared__ int   sidx2[2][4];
    __shared__ int   sKnn[KNN_K];
    __shared__ float sTokA[DDIM];
    __shared__ float sTokN[KNN_K][DDIM];
    __shared__ float sAH[64];
    __shared__ float sHid[KNN_K][64];
    __shared__ float sSc[KNN_K];

    // ---------------- Phase A: KNN, faithful fp32 d2 ----------------
    const float qx = cb[v * 3 + 0];
    const float qy = cb[v * 3 + 1];
    const float qz = cb[v * 3 + 2];
    const float sqq = f_sq3(qx, qy, qz);

    float d2[16];
    #pragma unroll
    for (int i = 0; i < 16; i++) {
        int j = tid + i * 256;
        float xj = cb[j * 3 + 0], yj = cb[j * 3 + 1], zj = cb[j * 3 + 2];
        float sqj = f_sq3(xj, yj, zj);
        float dt  = f_dot3(qx, qy, qz, xj, yj, zj);
        d2[i] = __fsub_rn(__fadd_rn(sqq, sqj), __fmul_rn(2.0f, dt));
    }

    // cached per-thread local best; rescans only when own candidate removed
    unsigned used = 0;
    float best = 3.4e38f;
    int   bi   = 0x7fffffff;
    #pragma unroll
    for (int i = 0; i < 16; i++) {
        if (d2[i] < best) { best = d2[i]; bi = tid + i * 256; }   // strict <: lowest idx
    }

    for (int it = 0; it < 11; it++) {
        float rb = best;
        int   ri = bi;
        #pragma unroll
        for (int off = 1; off < 64; off <<= 1) {      // wave butterfly argmin (order-free)
            float v2 = __shfl_xor(rb, off);
            int   i2 = __shfl_xor(ri, off);
            if (v2 < rb || (v2 == rb && i2 < ri)) { rb = v2; ri = i2; }
        }
        const int p = it & 1;
        if (lane == 0) { sval2[p][wave] = rb; sidx2[p][wave] = ri; }
        __syncthreads();
        float fb = sval2[p][0]; int fi = sidx2[p][0];
        #pragma unroll
        for (int w2 = 1; w2 < 4; w2++) {
            float v2 = sval2[p][w2]; int i2 = sidx2[p][w2];
            if (v2 < fb || (v2 == fb && i2 < fi)) { fb = v2; fi = i2; }
        }
        int w = fi & 4095;    // defense clamp
        if (it >= 1 && tid == 0) sKnn[it - 1] = w;
        if ((w & 255) == tid) {           // winner thread only: mask + rescan
            used |= 1u << (w >> 8);
            best = 3.4e38f; bi = 0x7fffffff;
            #pragma unroll
            for (int i = 0; i < 16; i++) {
                if (used & (1u << i)) continue;
                if (d2[i] < best) { best = d2[i]; bi = tid + i * 256; }
            }
        }
        // parity double-buffer: next round writes the other slot, 1 barrier/round
    }
    __syncthreads();          // publish sKnn

    // ---------------- Phase B: score MLP, faithful fp32 ----------------
    sTokA[tid] = tok[(size_t)q * DDIM + tid];
    for (int nb = 0; nb < KNN_K; nb++)
        sTokN[nb][tid] = tok[(size_t)(base + sKnn[nb]) * DDIM + tid];
    __syncthreads();

    if (tid < 64) {           // anchor-prefix chain (identical rounding for all nb)
        const float* wA = W1 + tid;
        float a = 0.0f;
        #pragma unroll 16
        for (int k = 0; k < 256; k++)
            a = __fmaf_rn(sTokA[k], wA[k * 64], a);
        sAH[tid] = a;
    }
    __syncthreads();

    for (int idx = tid; idx < KNN_K * 64; idx += 256) {
        int nb = idx >> 6, h = idx & 63;
        float acc = sAH[h];
        const float* tn = sTokN[nb];
        const float* wN = W1 + 256 * 64 + h;
        #pragma unroll 16
        for (int k = 0; k < 256; k++)
            acc = __fmaf_rn(tn[k], wN[k * 64], acc);
        #pragma unroll
        for (int c = 0; c < 3; c++) {
            float rel = __fsub_rn(cb[sKnn[nb] * 3 + c], cb[v * 3 + c]);
            acc = __fmaf_rn(rel, W1[(512 + c) * 64 + h], acc);
        }
        float hid = __fadd_rn(acc, b1[h]);
        sHid[nb][h] = hid > 0.0f ? hid : 0.0f;
    }
    __syncthreads();

    if (tid < KNN_K) {
        float s = 0.0f;
        for (int h = 0; h < 64; h++)
            s = __fmaf_rn(sHid[tid][h], W2[h], s);
        sSc[tid] = s;
    }
    __syncthreads();

    if (tid == 0) {           // stable top-4 -> global rows
        unsigned um = 0;
        #pragma unroll
        for (int s = 0; s < TK; s++) {
            float bests = -3.4e38f; int bj = 0;
            for (int jj = 0; jj < KNN_K; jj++) {
                if (um & (1u << jj)) continue;
                if (sSc[jj] > bests) { bests = sSc[jj]; bj = jj; }
            }
            um |= 1u << bj;
            sel[(size_t)q * TK + s] = base + sKnn[bj];
        }
    }
}

// ===========================================================================
// K2: dense QKV projection GEMM. qkv[m][g*256+n] = tok[m,:] @ Wg[:,n] + bg[n]
// M=16384, N=768 (Q|K|V), K=256. grid(256,12), block 256, 64x64/BK16/4x4.
// ===========================================================================
__global__ void __launch_bounds__(256) qkv_gemm_kernel(
    const float* __restrict__ tok,
    const float* __restrict__ Wq, const float* __restrict__ bq,
    const float* __restrict__ Wk, const float* __restrict__ bk,
    const float* __restrict__ Wv, const float* __restrict__ bv,
    float* __restrict__ qkv)
{
    __shared__ float As[16][68];   // [k][m]
    __shared__ float Bs[16][68];   // [k][n]

    const int mBlock = blockIdx.x * 64;
    const int nBlock = blockIdx.y * 64;      // 0..704
    const int grp = nBlock >> 8;             // 0=Q,1=K,2=V
    const int nIn = nBlock & 255;
    const float* W    = (grp == 0) ? Wq : (grp == 1) ? Wk : Wv;
    const float* bias = (grp == 0) ? bq : (grp == 1) ? bk : bv;

    const int tid = threadIdx.x;
    const int tx = tid & 15;     // n-dir
    const int ty = tid >> 4;     // m-dir

    const int ar  = tid >> 2;          // 0..63 (m row)
    const int ac4 = tid & 3;           // 0..3  (k float4)
    const int br  = tid >> 4;          // 0..15 (k row)
    const int bc4 = tid & 15;          // 0..15 (n float4)

    float acc[4][4] = {};

    for (int k0 = 0; k0 < 256; k0 += 16) {
        float4 a4 = *(const float4*)&tok[(size_t)(mBlock + ar) * 256 + k0 + ac4 * 4];
        As[ac4 * 4 + 0][ar] = a4.x;
        As[ac4 * 4 + 1][ar] = a4.y;
        As[ac4 * 4 + 2][ar] = a4.z;
        As[ac4 * 4 + 3][ar] = a4.w;
        float4 b4 = *(const float4*)&W[(size_t)(k0 + br) * 256 + nIn + bc4 * 4];
        *(float4*)&Bs[br][bc4 * 4] = b4;
        __syncthreads();
        #pragma unroll
        for (int kk = 0; kk < 16; kk++) {
            float4 av = *(const float4*)&As[kk][ty * 4];
            float4 bv4 = *(const float4*)&Bs[kk][tx * 4];
            acc[0][0] = fmaf(av.x, bv4.x, acc[0][0]); acc[0][1] = fmaf(av.x, bv4.y, acc[0][1]);
            acc[0][2] = fmaf(av.x, bv4.z, acc[0][2]); acc[0][3] = fmaf(av.x, bv4.w, acc[0][3]);
            acc[1][0] = fmaf(av.y, bv4.x, acc[1][0]); acc[1][1] = fmaf(av.y, bv4.y, acc[1][1]);
            acc[1][2] = fmaf(av.y, bv4.z, acc[1][2]); acc[1][3] = fmaf(av.y, bv4.w, acc[1][3]);
            acc[2][0] = fmaf(av.z, bv4.x, acc[2][0]); acc[2][1] = fmaf(av.z, bv4.y, acc[2][1]);
            acc[2][2] = fmaf(av.z, bv4.z, acc[2][2]); acc[2][3] = fmaf(av.z, bv4.w, acc[2][3]);
            acc[3][0] = fmaf(av.w, bv4.x, acc[3][0]); acc[3][1] = fmaf(av.w, bv4.y, acc[3][1]);
            acc[3][2] = fmaf(av.w, bv4.z, acc[3][2]); acc[3][3] = fmaf(av.w, bv4.w, acc[3][3]);
        }
        __syncthreads();
    }

    #pragma unroll
    for (int i = 0; i < 4; i++) {
        int m = mBlock + ty * 4 + i;
        float4 o;
        o.x = acc[i][0] + bias[nIn + tx * 4 + 0];
        o.y = acc[i][1] + bias[nIn + tx * 4 + 1];
        o.z = acc[i][2] + bias[nIn + tx * 4 + 2];
        o.w = acc[i][3] + bias[nIn + tx * 4 + 3];
        *(float4*)&qkv[(size_t)m * 768 + nBlock + tx * 4] = o;
    }
}

// ===========================================================================
// K3: gather 4 selected K/V rows, 4-head attention -> attnout[q][256].
// ===========================================================================
__global__ void __launch_bounds__(256) attn_gather_kernel(
    const float* __restrict__ qkv, const int* __restrict__ sel,
    float* __restrict__ attnout)
{
    const int q = blockIdx.x;
    const int tid = threadIdx.x;  // = h*64 + dh

    const float qv = qkv[(size_t)q * 768 + tid];

    int rows[TK];
    #pragma unroll
    for (int s = 0; s < TK; s++) rows[s] = sel[(size_t)q * TK + s];

    float att[TK];
    #pragma unroll
    for (int s = 0; s < TK; s++) {
        float p = qv * qkv[(size_t)rows[s] * 768 + 256 + tid];
        #pragma unroll
        for (int m = 1; m < 64; m <<= 1) p += __shfl_xor(p, m);
        att[s] = p * 0.125f;   // 1/sqrt(64)
    }

    float mx  = fmaxf(fmaxf(att[0], att[1]), fmaxf(att[2], att[3]));
    float e0 = expf(att[0] - mx), e1 = expf(att[1] - mx),
          e2 = expf(att[2] - mx), e3 = expf(att[3] - mx);
    float inv = 1.0f / (e0 + e1 + e2 + e3);

    float o = (e0 * qkv[(size_t)rows[0] * 768 + 512 + tid] +
               e1 * qkv[(size_t)rows[1] * 768 + 512 + tid] +
               e2 * qkv[(size_t)rows[2] * 768 + 512 + tid] +
               e3 * qkv[(size_t)rows[3] * 768 + 512 + tid]) * inv;

    attnout[(size_t)q * 256 + tid] = o;
}

// ===========================================================================
// K4: output projection GEMM. out = attnout @ Wo + bo. M=16384,N=256,K=256.
// ===========================================================================
__global__ void __launch_bounds__(256) wo_gemm_kernel(
    const float* __restrict__ A,
    const float* __restrict__ Wo, const float* __restrict__ bo,
    float* __restrict__ out)
{
    __shared__ float As[16][68];
    __shared__ float Bs[16][68];

    const int mBlock = blockIdx.x * 64;
    const int nBlock = blockIdx.y * 64;      // 0..192

    const int tid = threadIdx.x;
    const int tx = tid & 15;
    const int ty = tid >> 4;

    const int ar  = tid >> 2;
    const int ac4 = tid & 3;
    const int br  = tid >> 4;
    const int bc4 = tid & 15;

    float acc[4][4] = {};

    for (int k0 = 0; k0 < 256; k0 += 16) {
        float4 a4 = *(const float4*)&A[(size_t)(mBlock + ar) * 256 + k0 + ac4 * 4];
        As[ac4 * 4 + 0][ar] = a4.x;
        As[ac4 * 4 + 1][ar] = a4.y;
        As[ac4 * 4 + 2][ar] = a4.z;
        As[ac4 * 4 + 3][ar] = a4.w;
        float4 b4 = *(const float4*)&Wo[(size_t)(k0 + br) * 256 + nBlock + bc4 * 4];
        *(float4*)&Bs[br][bc4 * 4] = b4;
        __syncthreads();
        #pragma unroll
        for (int kk = 0; kk < 16; kk++) {
            float4 av = *(const float4*)&As[kk][ty * 4];
            float4 bv4 = *(const float4*)&Bs[kk][tx * 4];
            acc[0][0] = fmaf(av.x, bv4.x, acc[0][0]); acc[0][1] = fmaf(av.x, bv4.y, acc[0][1]);
            acc[0][2] = fmaf(av.x, bv4.z, acc[0][2]); acc[0][3] = fmaf(av.x, bv4.w, acc[0][3]);
            acc[1][0] = fmaf(av.y, bv4.x, acc[1][0]); acc[1][1] = fmaf(av.y, bv4.y, acc[1][1]);
            acc[1][2] = fmaf(av.y, bv4.z, acc[1][2]); acc[1][3] = fmaf(av.y, bv4.w, acc[1][3]);
            acc[2][0] = fmaf(av.z, bv4.x, acc[2][0]); acc[2][1] = fmaf(av.z, bv4.y, acc[2][1]);
            acc[2][2] = fmaf(av.z, bv4.z, acc[2][2]); acc[2][3] = fmaf(av.z, bv4.w, acc[2][3]);
            acc[3][0] = fmaf(av.w, bv4.x, acc[3][0]); acc[3][1] = fmaf(av.w, bv4.y, acc[3][1]);
            acc[3][2] = fmaf(av.w, bv4.z, acc[3][2]); acc[3][3] = fmaf(av.w, bv4.w, acc[3][3]);
        }
        __syncthreads();
    }

    #pragma unroll
    for (int i = 0; i < 4; i++) {
        int m = mBlock + ty * 4 + i;
        float4 o;
        o.x = acc[i][0] + bo[nBlock + tx * 4 + 0];
        o.y = acc[i][1] + bo[nBlock + tx * 4 + 1];
        o.z = acc[i][2] + bo[nBlock + tx * 4 + 2];
        o.w = acc[i][3] + bo[nBlock + tx * 4 + 3];
        *(float4*)&out[(size_t)m * 256 + nBlock + tx * 4] = o;
    }
}

// ===========================================================================
// Fallback: round-9 fully fused kernel (PASSED @1050us), used if ws too small.
// ===========================================================================
__global__ void __launch_bounds__(256) fused_voxel_attn(
    const float* __restrict__ tok,
    const float* __restrict__ coords,
    const float* __restrict__ W1,
    const float* __restrict__ b1,
    const float* __restrict__ W2,
    const float* __restrict__ Wq, const float* __restrict__ bq,
    const float* __restrict__ Wk, const float* __restrict__ bk,
    const float* __restrict__ Wv, const float* __restrict__ bv,
    const float* __restrict__ Wo, const float* __restrict__ bo,
    float* __restrict__ out, int out_size)
{
    const int q    = blockIdx.x;
    const int b    = q >> 12;
    const int v    = q & 4095;
    const int base = q & ~4095;
    const int tid  = threadIdx.x;
    const float* cb = coords + (size_t)b * VV * 3;

    __shared__ float  sval[256];
    __shared__ int    sidx[256];
    __shared__ int    sKnn[KNN_K];
    __shared__ int    sSel[TK];
    __shared__ float  sTokA[DDIM];
    __shared__ float  sTokN[KNN_K][DDIM];
    __shared__ float  sAH[64];
    __shared__ float  sHid[KNN_K][64];
    __shared__ float  sSc[KNN_K];
    __shared__ float  sP[TK][256];
    __shared__ float  sAtt[4][TK];
    __shared__ float  sO[DDIM];

    const float qx = cb[v * 3 + 0];
    const float qy = cb[v * 3 + 1];
    const float qz = cb[v * 3 + 2];
    const float sqq = f_sq3(qx, qy, qz);

    float d2[16];
    #pragma unroll
    for (int i = 0; i < 16; i++) {
        int j = tid + i * 256;
        float xj = cb[j * 3 + 0], yj = cb[j * 3 + 1], zj = cb[j * 3 + 2];
        float sqj = f_sq3(xj, yj, zj);
        float dt  = f_dot3(qx, qy, qz, xj, yj, zj);
        d2[i] = __fsub_rn(__fadd_rn(sqq, sqj), __fmul_rn(2.0f, dt));
    }

    unsigned used = 0;
    for (int it = 0; it < 11; it++) {
        float best = 3.4e38f;
        int bi = 0x7fffffff;
        #pragma unroll
        for (int i = 0; i < 16; i++) {
            if (used & (1u << i)) continue;
            if (d2[i] < best) { best = d2[i]; bi = tid + i * 256; }
        }
        sval[tid] = best;
        sidx[tid] = bi;
        __syncthreads();
        for (int s = 128; s > 0; s >>= 1) {
            if (tid < s) {
                float v2 = sval[tid + s];
                int   i2 = sidx[tid + s];
                if (v2 < sval[tid] || (v2 == sval[tid] && i2 < sidx[tid])) {
                    sval[tid] = v2; sidx[tid] = i2;
                }
            }
            __syncthreads();
        }
        int w = sidx[0] & 4095;
        __syncthreads();
        if (it >= 1 && tid == 0) sKnn[it - 1] = w;
        if ((w & 255) == tid) used |= 1u << (w >> 8);
    }
    __syncthreads();

    sTokA[tid] = tok[(size_t)q * DDIM + tid];
    for (int nb = 0; nb < KNN_K; nb++)
        sTokN[nb][tid] = tok[(size_t)(base + sKnn[nb]) * DDIM + tid];
    __syncthreads();

    if (tid < 64) {
        float a = 0.0f;
        for (int k = 0; k < 256; k++)
            a = __fmaf_rn(sTokA[k], W1[k * 64 + tid], a);
        sAH[tid] = a;
    }
    __syncthreads();

    for (int idx = tid; idx < KNN_K * 64; idx += 256) {
        int nb = idx >> 6;
        int h  = idx & 63;
        float acc = sAH[h];
        const float* tn = sTokN[nb];
        for (int k = 0; k < 256; k++)
            acc = __fmaf_rn(tn[k], W1[(256 + k) * 64 + h], acc);
        #pragma unroll
        for (int c = 0; c < 3; c++) {
            float rel = __fsub_rn(cb[sKnn[nb] * 3 + c], cb[v * 3 + c]);
            acc = __fmaf_rn(rel, W1[(512 + c) * 64 + h], acc);
        }
        float hid = __fadd_rn(acc, b1[h]);
        sHid[nb][h] = hid > 0.0f ? hid : 0.0f;
    }
    __syncthreads();

    if (tid < KNN_K) {
        float s = 0.0f;
        for (int h = 0; h < 64; h++)
            s = __fmaf_rn(sHid[tid][h], W2[h], s);
        sSc[tid] = s;
    }
    __syncthreads();

    if (tid == 0) {
        unsigned um = 0;
        #pragma unroll
        for (int s = 0; s < TK; s++) {
            float best = -3.4e38f; int bj = 0;
            for (int jj = 0; jj < KNN_K; jj++) {
                if (um & (1u << jj)) continue;
                if (sSc[jj] > best) { best = sSc[jj]; bj = jj; }
            }
            um |= 1u << bj;
            sSel[s] = bj;
        }
    }
    __syncthreads();

    int ss[TK];
    float k_acc[TK], v_acc[TK];
    #pragma unroll
    for (int s = 0; s < TK; s++) {
        ss[s] = sSel[s];
        k_acc[s] = bk[tid];
        v_acc[s] = bv[tid];
    }
    float q_acc = bq[tid];

    for (int k = 0; k < 256; k++) {
        float wq = Wq[k * 256 + tid];
        float wk = Wk[k * 256 + tid];
        float wv = Wv[k * 256 + tid];
        q_acc += sTokA[k] * wq;
        #pragma unroll
        for (int s = 0; s < TK; s++) {
            float x = sTokN[ss[s]][k];
            k_acc[s] += x * wk;
            v_acc[s] += x * wv;
        }
    }

    #pragma unroll
    for (int s = 0; s < TK; s++) sP[s][tid] = q_acc * k_acc[s];
    __syncthreads();

    if (tid < 16) {
        int h = tid >> 2, s = tid & 3;
        float p = 0.0f;
        for (int d = 0; d < 64; d++) p += sP[s][h * 64 + d];
        sAtt[h][s] = p * 0.125f;
    }
    __syncthreads();

    const int hh = tid >> 6;
    float a0 = sAtt[hh][0], a1 = sAtt[hh][1], a2 = sAtt[hh][2], a3 = sAtt[hh][3];
    float mx  = fmaxf(fmaxf(a0, a1), fmaxf(a2, a3));
    float e0 = expf(a0 - mx), e1 = expf(a1 - mx), e2 = expf(a2 - mx), e3 = expf(a3 - mx);
    float inv = 1.0f / (e0 + e1 + e2 + e3);
    float o = (e0 * v_acc[0] + e1 * v_acc[1] + e2 * v_acc[2] + e3 * v_acc[3]) * inv;

    sO[tid] = o;
    __syncthreads();

    float a = bo[tid];
    for (int e = 0; e < 256; e++) a += sO[e] * Wo[e * 256 + tid];
    int oidx = q * DDIM + tid;
    if (oidx < out_size)
        out[oidx] = a;
}

// ---------------------------------------------------------------------------
// Launcher. ABI-bilingual size-walk (validated r8-r11). ws layout:
//   sel     @ 0        : 16384*4*4   =   262,144
//   qkv     @ 4 MiB    : 16384*768*4 = 50,331,648  (ends 54,525,952)
//   attnout @ 56 MiB   : 16384*256*4 = 16,777,216  (ends 75,497,472)
// ws_size >= 75,497,472 confirmed in r11 (specialized path ran).
// ---------------------------------------------------------------------------
extern "C" void kernel_launch(void* const* d_in, const int* in_sizes, int n_in,
                              void* d_out, int out_size, void* d_ws, size_t ws_size,
                              hipStream_t stream)
{
    const long long want[13] = {4194304LL, 49152LL, 32960LL, 64LL, 64LL,
                                65536LL, 256LL, 65536LL, 256LL,
                                65536LL, 256LL, 65536LL, 256LL};
    int idx[13];
    const int n = n_in;

    const long long* s64 = (const long long*)(const void*)in_sizes;
    const int*       s32 = in_sizes;

    bool ok = false;

    if (n >= 13 && s64[0] == want[0]) {   // int64 interpretation (gated)
        ok = true;
        int walk = 0;
        for (int t = 0; t < 13; t++) {
            int f = -1;
            for (int i = walk; i < n; i++) {
                if (s64[i] == want[t]) { f = i; break; }
            }
            if (f < 0) { ok = false; break; }
            idx[t] = f; walk = f + 1;
        }
    }

    if (!ok) {                            // int32 interpretation
        ok = true;
        int walk = 0;
        for (int t = 0; t < 13; t++) {
            int f = -1;
            for (int i = walk; i < n; i++) {
                if ((long long)s32[i] == want[t]) { f = i; break; }
            }
            if (f < 0) { ok = false; break; }
            idx[t] = f; walk = f + 1;
        }
    }

    if (!ok) return;   // unexpected layout: clean failure, no crash

    const float* tok    = (const float*)d_in[idx[0]];
    const float* coords = (const float*)d_in[idx[1]];
    const float* W1     = (const float*)d_in[idx[2]];
    const float* b1     = (const float*)d_in[idx[3]];
    const float* W2     = (const float*)d_in[idx[4]];
    const float* Wq     = (const float*)d_in[idx[5]];
    const float* bq     = (const float*)d_in[idx[6]];
    const float* Wk     = (const float*)d_in[idx[7]];
    const float* bk     = (const float*)d_in[idx[8]];
    const float* Wv     = (const float*)d_in[idx[9]];
    const float* bv     = (const float*)d_in[idx[10]];
    const float* Wo     = (const float*)d_in[idx[11]];
    const float* bo     = (const float*)d_in[idx[12]];
    float* out = (float*)d_out;

    const size_t NEED = 75497472;   // attnout end
    if (ws_size >= NEED) {
        char* ws = (char*)d_ws;
        int*   sel     = (int*)  (ws + 0);
        float* qkv     = (float*)(ws + 4194304);
        float* attnout = (float*)(ws + 58720256);

        knn_score_kernel<<<dim3(16384), dim3(256), 0, stream>>>(tok, coords, W1, b1, W2, sel);
        qkv_gemm_kernel<<<dim3(256, 12), dim3(256), 0, stream>>>(tok, Wq, bq, Wk, bk, Wv, bv, qkv);
        attn_gather_kernel<<<dim3(16384), dim3(256), 0, stream>>>(qkv, sel, attnout);
        wo_gemm_kernel<<<dim3(256, 4), dim3(256), 0, stream>>>(attnout, Wo, bo, out);
    } else {
        fused_voxel_attn<<<dim3(16384), dim3(256), 0, stream>>>(
            tok, coords, W1, b1, W2, Wq, bq, Wk, bk, Wv, bv, Wo, bo, out, out_size);
    }
}